// Round 1
// baseline (631.098 us; speedup 1.0000x reference)
//
#include <hip/hip_runtime.h>
#include <hip/hip_bf16.h>

// LQLinear: out = x @ quantize(weight, basis)^T + bias
// M=8192 tokens, N=4096 out_features, K=4096 in_features.
// Q_T=1 and new_basis is discarded => the LSQ refit does NOT affect output.

#define M_TOK 8192
#define N_OUT 4096
#define K_IN  4096

typedef __attribute__((ext_vector_type(8))) short short8;   // 8 bf16 (4 VGPRs)
typedef __attribute__((ext_vector_type(4))) float floatx4;  // MFMA C/D frag

typedef __attribute__((address_space(1))) const void gvoid_t;
typedef __attribute__((address_space(3))) void lvoid_t;

// round-to-nearest-even fp32 -> bf16 (bit trick; no NaN in this data)
__device__ __forceinline__ ushort f2bf(float f) {
    unsigned u = __float_as_uint(f);
    u += 0x7fffu + ((u >> 16) & 1u);
    return (ushort)(u >> 16);
}

// ---------------- x: fp32 -> bf16 ----------------
__global__ void cvt_f32_bf16(const float4* __restrict__ in,
                             ushort4* __restrict__ out, int n4) {
    int i = blockIdx.x * blockDim.x + threadIdx.x;
    if (i >= n4) return;
    float4 v = in[i];
    ushort4 o;
    o.x = f2bf(v.x); o.y = f2bf(v.y); o.z = f2bf(v.z); o.w = f2bf(v.w);
    out[i] = o;
}

// ---------------- weight: quantize to 4 levels, emit bf16 ----------------
__global__ void quant_w(const float4* __restrict__ w,
                        const float* __restrict__ basis,
                        ushort4* __restrict__ out, int n4) {
    int i = blockIdx.x * blockDim.x + threadIdx.x;
    if (i >= n4) return;
    float b0 = basis[0], b1 = basis[1];
    // levels = encodings({-1,+1}^2) @ [b0,b1], then sort ascending (network)
    float l0 = -b0 - b1, l1 = -b0 + b1, l2 = b0 - b1, l3 = b0 + b1;
    float t;
    if (l0 > l1) { t = l0; l0 = l1; l1 = t; }
    if (l2 > l3) { t = l2; l2 = l3; l3 = t; }
    if (l0 > l2) { t = l0; l0 = l2; l2 = t; }
    if (l1 > l3) { t = l1; l1 = l3; l3 = t; }
    if (l1 > l2) { t = l1; l1 = l2; l2 = t; }
    // midpoint thresholds; searchsorted 'left' => idx = #{thres < w}
    float t0 = 0.5f * (l0 + l1), t1 = 0.5f * (l1 + l2), t2 = 0.5f * (l2 + l3);
    float4 v = w[i];
    ushort4 o;
    float q;
    q = (v.x > t1) ? ((v.x > t2) ? l3 : l2) : ((v.x > t0) ? l1 : l0); o.x = f2bf(q);
    q = (v.y > t1) ? ((v.y > t2) ? l3 : l2) : ((v.y > t0) ? l1 : l0); o.y = f2bf(q);
    q = (v.z > t1) ? ((v.z > t2) ? l3 : l2) : ((v.z > t0) ? l1 : l0); o.z = f2bf(q);
    q = (v.w > t1) ? ((v.w > t2) ? l3 : l2) : ((v.w > t0) ? l1 : l0); o.w = f2bf(q);
    out[i] = o;
}

// ---------------- GEMM: C[M][N] = A[M][K] * B[N][K]^T + bias ----------------
// m97 structure: 128x128 block tile, BK=64, 4 waves in 2x2, each wave 4x4
// tiles of 16x16x32 MFMA. global_load_lds width=16 staging.
__global__ __launch_bounds__(256) void gemm_bt(
        const ushort* __restrict__ A,   // bf16 [M][K]
        const ushort* __restrict__ B,   // bf16 [N][K]
        const float* __restrict__ bias, // [N]
        float* __restrict__ C) {        // fp32 [M][N]
    __shared__ ushort As[128 * 64];
    __shared__ ushort Bs[128 * 64];

    const int lane = threadIdx.x & 63;
    const int wv   = threadIdx.x >> 6;      // 0..3
    const int bm0  = blockIdx.y * 128;
    const int bn0  = blockIdx.x * 128;
    const int wm   = (wv >> 1) * 64;        // wave row offset in block tile
    const int wn   = (wv & 1) * 64;         // wave col offset

    floatx4 acc[4][4] = {};

    // staging: per wave 4 instrs for A, 4 for B; each instr = 8 rows x 64 cols
    const int lr = lane >> 3;               // 0..7  (row within 8-row group)
    const int lc = lane & 7;                // 0..7  (16B chunk within row)
    const ushort* ag = A + (size_t)(bm0 + wv * 32 + lr) * K_IN + lc * 8;
    const ushort* bg = B + (size_t)(bn0 + wv * 32 + lr) * K_IN + lc * 8;
    ushort* asl = As + (wv * 32) * 64;      // wave-uniform LDS base
    ushort* bsl = Bs + (wv * 32) * 64;

    // MFMA fragment addressing (16x16x32): lane holds row lane&15, k quad*8..+7
    const int mrow = lane & 15;
    const int kq   = (lane >> 4) * 8;

    for (int kt = 0; kt < K_IN / 64; ++kt) {
#pragma unroll
        for (int t = 0; t < 4; ++t) {
            __builtin_amdgcn_global_load_lds((gvoid_t*)(ag + (size_t)t * 8 * K_IN),
                                             (lvoid_t*)(asl + t * 8 * 64), 16, 0, 0);
            __builtin_amdgcn_global_load_lds((gvoid_t*)(bg + (size_t)t * 8 * K_IN),
                                             (lvoid_t*)(bsl + t * 8 * 64), 16, 0, 0);
        }
        ag += 64; bg += 64;
        __syncthreads();
#pragma unroll
        for (int ks = 0; ks < 2; ++ks) {
            short8 af[4], bfv[4];
#pragma unroll
            for (int i = 0; i < 4; ++i)
                af[i] = *(const short8*)(As + (wm + i * 16 + mrow) * 64 + ks * 32 + kq);
#pragma unroll
            for (int j = 0; j < 4; ++j)
                bfv[j] = *(const short8*)(Bs + (wn + j * 16 + mrow) * 64 + ks * 32 + kq);
#pragma unroll
            for (int i = 0; i < 4; ++i)
#pragma unroll
                for (int j = 0; j < 4; ++j)
                    acc[i][j] = __builtin_amdgcn_mfma_f32_16x16x32_bf16(
                        af[i], bfv[j], acc[i][j], 0, 0, 0);
        }
        __syncthreads();
    }

    // epilogue: C/D layout col=lane&15, row=(lane>>4)*4+reg
    const int r0 = (lane >> 4) * 4;
    const int cc = lane & 15;
#pragma unroll
    for (int j = 0; j < 4; ++j) {
        const int col = bn0 + wn + j * 16 + cc;
        const float bj = bias[col];
#pragma unroll
        for (int i = 0; i < 4; ++i) {
#pragma unroll
            for (int r = 0; r < 4; ++r) {
                const int row = bm0 + wm + i * 16 + r0 + r;
                C[(size_t)row * N_OUT + col] = acc[i][j][r] + bj;
            }
        }
    }
}

extern "C" void kernel_launch(void* const* d_in, const int* in_sizes, int n_in,
                              void* d_out, int out_size, void* d_ws, size_t ws_size,
                              hipStream_t stream) {
    const float* x     = (const float*)d_in[0];  // [8192,4096]
    const float* w     = (const float*)d_in[1];  // [4096,4096]
    const float* bias  = (const float*)d_in[2];  // [4096]
    const float* basis = (const float*)d_in[3];  // [2]
    float* out = (float*)d_out;                  // [8192,4096] fp32

    ushort* Xb = (ushort*)d_ws;                      // 8192*4096 bf16 = 67.1 MB
    ushort* Wq = Xb + (size_t)M_TOK * K_IN;          // 4096*4096 bf16 = 33.5 MB

    {
        int n4 = (M_TOK * K_IN) / 4;                 // 8388608
        cvt_f32_bf16<<<n4 / 256, 256, 0, stream>>>((const float4*)x, (ushort4*)Xb, n4);
    }
    {
        int n4 = (N_OUT * K_IN) / 4;                 // 4194304
        quant_w<<<n4 / 256, 256, 0, stream>>>((const float4*)w, basis, (ushort4*)Wq, n4);
    }
    {
        dim3 grid(N_OUT / 128, M_TOK / 128);         // (32, 64)
        gemm_bt<<<grid, 256, 0, stream>>>(Xb, Wq, bias, out);
    }
}

// Round 2
// 557.387 us; speedup vs baseline: 1.1322x; 1.1322x over previous
//
#include <hip/hip_runtime.h>
#include <hip/hip_bf16.h>

// LQLinear: out = x @ quantize(weight, basis)^T + bias
// M=8192 tokens, N=4096 out_features, K=4096 in_features.
// Q_T=1 and new_basis is discarded => the LSQ refit does NOT affect output.

#define M_TOK 8192
#define N_OUT 4096
#define K_IN  4096

typedef __attribute__((ext_vector_type(8))) short short8;   // 8 bf16 (4 VGPRs)
typedef __attribute__((ext_vector_type(4))) float floatx4;  // MFMA C/D frag

typedef __attribute__((address_space(1))) const void gvoid_t;
typedef __attribute__((address_space(3))) void lvoid_t;

// round-to-nearest-even fp32 -> bf16 (bit trick; no NaN in this data)
__device__ __forceinline__ ushort f2bf(float f) {
    unsigned u = __float_as_uint(f);
    u += 0x7fffu + ((u >> 16) & 1u);
    return (ushort)(u >> 16);
}

// ---------------- x: fp32 -> bf16 ----------------
__global__ void cvt_f32_bf16(const float4* __restrict__ in,
                             ushort4* __restrict__ out, int n4) {
    int i = blockIdx.x * blockDim.x + threadIdx.x;
    if (i >= n4) return;
    float4 v = in[i];
    ushort4 o;
    o.x = f2bf(v.x); o.y = f2bf(v.y); o.z = f2bf(v.z); o.w = f2bf(v.w);
    out[i] = o;
}

// ---------------- weight: quantize to 4 levels, emit bf16 ----------------
__global__ void quant_w(const float4* __restrict__ w,
                        const float* __restrict__ basis,
                        ushort4* __restrict__ out, int n4) {
    int i = blockIdx.x * blockDim.x + threadIdx.x;
    if (i >= n4) return;
    float b0 = basis[0], b1 = basis[1];
    // levels = encodings({-1,+1}^2) @ [b0,b1], then sort ascending (network)
    float l0 = -b0 - b1, l1 = -b0 + b1, l2 = b0 - b1, l3 = b0 + b1;
    float t;
    if (l0 > l1) { t = l0; l0 = l1; l1 = t; }
    if (l2 > l3) { t = l2; l2 = l3; l3 = t; }
    if (l0 > l2) { t = l0; l0 = l2; l2 = t; }
    if (l1 > l3) { t = l1; l1 = l3; l3 = t; }
    if (l1 > l2) { t = l1; l1 = l2; l2 = t; }
    // midpoint thresholds; searchsorted 'left' => idx = #{thres < w}
    float t0 = 0.5f * (l0 + l1), t1 = 0.5f * (l1 + l2), t2 = 0.5f * (l2 + l3);
    float4 v = w[i];
    ushort4 o;
    float q;
    q = (v.x > t1) ? ((v.x > t2) ? l3 : l2) : ((v.x > t0) ? l1 : l0); o.x = f2bf(q);
    q = (v.y > t1) ? ((v.y > t2) ? l3 : l2) : ((v.y > t0) ? l1 : l0); o.y = f2bf(q);
    q = (v.z > t1) ? ((v.z > t2) ? l3 : l2) : ((v.z > t0) ? l1 : l0); o.z = f2bf(q);
    q = (v.w > t1) ? ((v.w > t2) ? l3 : l2) : ((v.w > t0) ? l1 : l0); o.w = f2bf(q);
    out[i] = o;
}

// ---------------- GEMM: C[M][N] = A[M][K] * B[N][K]^T + bias ----------------
// m97 structure: 128x128 block tile, BK=64, 4 waves in 2x2, each wave 4x4
// tiles of 16x16x32 MFMA. global_load_lds width=16 staging.
// LDS XOR swizzle at 16B-chunk granularity: physical chunk c of row r holds
// global chunk (c ^ (r&7)). Breaks the 128B-row-stride 16-way bank conflict
// (all quad lanes previously hit one 4-bank group) down to free 2-way.
__global__ __launch_bounds__(256) void gemm_bt(
        const ushort* __restrict__ A,   // bf16 [M][K]
        const ushort* __restrict__ B,   // bf16 [N][K]
        const float* __restrict__ bias, // [N]
        float* __restrict__ C) {        // fp32 [M][N]
    __shared__ ushort As[128 * 64];
    __shared__ ushort Bs[128 * 64];

    const int lane = threadIdx.x & 63;
    const int wv   = threadIdx.x >> 6;      // 0..3
    const int bm0  = blockIdx.y * 128;
    const int bn0  = blockIdx.x * 128;
    const int wm   = (wv >> 1) * 64;        // wave row offset in block tile
    const int wn   = (wv & 1) * 64;         // wave col offset

    floatx4 acc[4][4] = {};

    // staging: per wave 4 instrs for A, 4 for B; each instr = 8 rows x 64 cols
    const int lr = lane >> 3;               // 0..7  (row within 8-row group)
    const int lc = lane & 7;                // 0..7  (16B chunk within row)
    // XOR swizzle: this lane's LDS slot (row lr, chunk lc) must receive
    // global chunk (lc ^ lr) of row lr.
    const ushort* ag = A + (size_t)(bm0 + wv * 32 + lr) * K_IN + (lc ^ lr) * 8;
    const ushort* bg = B + (size_t)(bn0 + wv * 32 + lr) * K_IN + (lc ^ lr) * 8;
    ushort* asl = As + (wv * 32) * 64;      // wave-uniform LDS base
    ushort* bsl = Bs + (wv * 32) * 64;

    // MFMA fragment addressing (16x16x32): lane holds row lane&15, k quad*8..+7
    const int mrow = lane & 15;
    const int quad = lane >> 4;             // 0..3
    // physical chunk for ks: ((quad | ks*4) ^ (mrow&7)) == (quad^(mrow&7)) ^ ks*4
    const int cswz = (quad ^ (mrow & 7)) * 8;   // ushort offset, ks adds 32

    for (int kt = 0; kt < K_IN / 64; ++kt) {
#pragma unroll
        for (int t = 0; t < 4; ++t) {
            __builtin_amdgcn_global_load_lds((gvoid_t*)(ag + (size_t)t * 8 * K_IN),
                                             (lvoid_t*)(asl + t * 8 * 64), 16, 0, 0);
            __builtin_amdgcn_global_load_lds((gvoid_t*)(bg + (size_t)t * 8 * K_IN),
                                             (lvoid_t*)(bsl + t * 8 * 64), 16, 0, 0);
        }
        ag += 64; bg += 64;
        __syncthreads();
#pragma unroll
        for (int ks = 0; ks < 2; ++ks) {
            short8 af[4], bfv[4];
#pragma unroll
            for (int i = 0; i < 4; ++i)
                af[i] = *(const short8*)(As + (wm + i * 16 + mrow) * 64 + (cswz ^ (ks * 32)));
#pragma unroll
            for (int j = 0; j < 4; ++j)
                bfv[j] = *(const short8*)(Bs + (wn + j * 16 + mrow) * 64 + (cswz ^ (ks * 32)));
#pragma unroll
            for (int i = 0; i < 4; ++i)
#pragma unroll
                for (int j = 0; j < 4; ++j)
                    acc[i][j] = __builtin_amdgcn_mfma_f32_16x16x32_bf16(
                        af[i], bfv[j], acc[i][j], 0, 0, 0);
        }
        __syncthreads();
    }

    // epilogue: C/D layout col=lane&15, row=(lane>>4)*4+reg
    const int r0 = (lane >> 4) * 4;
    const int cc = lane & 15;
#pragma unroll
    for (int j = 0; j < 4; ++j) {
        const int col = bn0 + wn + j * 16 + cc;
        const float bj = bias[col];
#pragma unroll
        for (int i = 0; i < 4; ++i) {
#pragma unroll
            for (int r = 0; r < 4; ++r) {
                const int row = bm0 + wm + i * 16 + r0 + r;
                C[(size_t)row * N_OUT + col] = acc[i][j][r] + bj;
            }
        }
    }
}

extern "C" void kernel_launch(void* const* d_in, const int* in_sizes, int n_in,
                              void* d_out, int out_size, void* d_ws, size_t ws_size,
                              hipStream_t stream) {
    const float* x     = (const float*)d_in[0];  // [8192,4096]
    const float* w     = (const float*)d_in[1];  // [4096,4096]
    const float* bias  = (const float*)d_in[2];  // [4096]
    const float* basis = (const float*)d_in[3];  // [2]
    float* out = (float*)d_out;                  // [8192,4096] fp32

    ushort* Xb = (ushort*)d_ws;                      // 8192*4096 bf16 = 67.1 MB
    ushort* Wq = Xb + (size_t)M_TOK * K_IN;          // 4096*4096 bf16 = 33.5 MB

    {
        int n4 = (M_TOK * K_IN) / 4;                 // 8388608
        cvt_f32_bf16<<<n4 / 256, 256, 0, stream>>>((const float4*)x, (ushort4*)Xb, n4);
    }
    {
        int n4 = (N_OUT * K_IN) / 4;                 // 4194304
        quant_w<<<n4 / 256, 256, 0, stream>>>((const float4*)w, basis, (ushort4*)Wq, n4);
    }
    {
        dim3 grid(N_OUT / 128, M_TOK / 128);         // (32, 64)
        gemm_bt<<<grid, 256, 0, stream>>>(Xb, Wq, bias, out);
    }
}